// Round 8
// baseline (118.741 us; speedup 1.0000x reference)
//
#include <hip/hip_runtime.h>

#define IMG_SIZE 2048
#define NPIX (IMG_SIZE * IMG_SIZE)
#define NBANDS 256
#define BAND_PIX (NPIX / NBANDS)   // 16384 pixels = 64 KB LDS u32

// ---- Scheme J: block-major binning (write locality) + streaming resolve ----
// Bin entry u64 = (pos14 << 32) | key32 ; key32 = (i+1)<<8 | q8(value).
// max(key32) per pixel == max point index i == numpy last-write-wins.
// q8 dequant err <= ~1/512 << 2e-2 threshold. key32 == 0 <=> untouched pixel.
#define H_TPB 256
#define H_PPT 32
#define H_CHUNK (H_TPB * H_PPT)    // 8192 points/block -> mean 32/band
#define H_CAP 40                   // pairs/run = 20 (even -> ulonglong2 never straddles)
#define H_NB 4
#define H_BP 8
#define BOF_SLOTS 2048             // per-band overflow list (mean ~170 used)
#define SP_CAP 4096                // global spill (expected 0 entries)

__global__ __launch_bounds__(H_TPB) void scatter_j_kernel(
    const float* __restrict__ x, unsigned long long* __restrict__ bins,
    unsigned int* __restrict__ counts, unsigned long long* __restrict__ bof,
    unsigned int* __restrict__ bof_cur, unsigned long long* __restrict__ spill,
    unsigned int* __restrict__ spill_cur, int n, int NB) {
    __shared__ unsigned int hist[NBANDS];
    const int tid = threadIdx.x;          // H_TPB == NBANDS == 256
    const int B = blockIdx.x;
    hist[tid] = 0;
    __syncthreads();

    const int block_base = B * H_CHUNK;
    const size_t run_base = (size_t)B * NBANDS * H_CAP;  // block-major: 80 KB/block

    if (block_base + H_CHUNK <= n) {
        // ---------- fast path: full chunk ----------
#pragma unroll
        for (int g = 0; g < H_NB; ++g) {
            const int p0 = block_base + g * (H_TPB * H_BP) + tid * H_BP;
            const float4* p = reinterpret_cast<const float4*>(x + (size_t)p0 * 3);
            float xs[24];
#pragma unroll
            for (int q = 0; q < 6; ++q) {
                const float4 v = p[q];
                xs[4*q+0] = v.x; xs[4*q+1] = v.y; xs[4*q+2] = v.z; xs[4*q+3] = v.w;
            }
            unsigned int bnd[H_BP], pos[H_BP], key[H_BP], r[H_BP];
#pragma unroll
            for (int j = 0; j < H_BP; ++j) {
                int i0 = (int)floorf(xs[3*j+0] * (float)IMG_SIZE);
                int i1 = (int)floorf(xs[3*j+1] * (float)IMG_SIZE);
                i0 = min(max(i0, 0), IMG_SIZE - 1);
                i1 = min(max(i1, 0), IMG_SIZE - 1);
                int q8 = (int)(xs[3*j+2] * 256.0f);
                q8 = min(max(q8, 0), 255);
                bnd[j] = (unsigned int)(i0 >> 3);
                pos[j] = (((unsigned int)i0 & 7u) << 11) | (unsigned int)i1;
                key[j] = (((unsigned int)(p0 + j) + 1u) << 8) | (unsigned int)q8;
            }
            // 8 independent LDS atomics -> pipelined
#pragma unroll
            for (int j = 0; j < H_BP; ++j) r[j] = atomicAdd(&hist[bnd[j]], 1u);
#pragma unroll
            for (int j = 0; j < H_BP; ++j) {
                if (r[j] < H_CAP) {
                    // block-major: this block's writes stay inside one 80 KB region
                    bins[run_base + (size_t)bnd[j] * H_CAP + r[j]] =
                        ((unsigned long long)pos[j] << 32) | (unsigned long long)key[j];
                } else {
                    // per-band overflow list (~170 atomics/address total: cheap)
                    const unsigned int s = atomicAdd(&bof_cur[bnd[j]], 1u);
                    if (s < BOF_SLOTS) {
                        bof[(size_t)bnd[j] * BOF_SLOTS + s] =
                            ((unsigned long long)pos[j] << 32) | (unsigned long long)key[j];
                    } else {  // pathological-only
                        const unsigned int gs = atomicAdd(spill_cur, 1u);
                        if (gs < SP_CAP)
                            spill[gs] =
                                ((unsigned long long)((bnd[j] << 14) | pos[j]) << 32) |
                                (unsigned long long)key[j];
                    }
                }
            }
        }
    } else {
        // ---------- guarded tail path ----------
        const int hi = min(n, block_base + H_CHUNK);
        for (int i = block_base + tid; i < hi; i += H_TPB) {
            const float fx = x[3*i], fy = x[3*i+1], fv = x[3*i+2];
            int i0 = min(max((int)floorf(fx * (float)IMG_SIZE), 0), IMG_SIZE - 1);
            int i1 = min(max((int)floorf(fy * (float)IMG_SIZE), 0), IMG_SIZE - 1);
            int q8 = min(max((int)(fv * 256.0f), 0), 255);
            const unsigned int band = (unsigned int)(i0 >> 3);
            const unsigned int pos = (((unsigned int)i0 & 7u) << 11) | (unsigned int)i1;
            const unsigned int key = (((unsigned int)i + 1u) << 8) | (unsigned int)q8;
            const unsigned int r = atomicAdd(&hist[band], 1u);
            if (r < H_CAP) {
                bins[run_base + (size_t)band * H_CAP + r] =
                    ((unsigned long long)pos << 32) | (unsigned long long)key;
            } else {
                const unsigned int s = atomicAdd(&bof_cur[band], 1u);
                if (s < BOF_SLOTS) {
                    bof[(size_t)band * BOF_SLOTS + s] =
                        ((unsigned long long)pos << 32) | (unsigned long long)key;
                } else {
                    const unsigned int gs = atomicAdd(spill_cur, 1u);
                    if (gs < SP_CAP)
                        spill[gs] = ((unsigned long long)((band << 14) | pos) << 32) |
                                    (unsigned long long)key;
                }
            }
        }
    }
    __syncthreads();
    counts[(size_t)tid * NB + B] = hist[tid];  // band-major counts for resolve prefetch
}

__global__ __launch_bounds__(1024) void resolve_j_kernel(
    const unsigned long long* __restrict__ bins,
    const unsigned int* __restrict__ counts,
    const unsigned long long* __restrict__ bof,
    const unsigned int* __restrict__ bof_cur,
    const unsigned long long* __restrict__ spill,
    const unsigned int* __restrict__ spill_cur,
    float* __restrict__ out, int NB) {
    __shared__ unsigned int img[BAND_PIX];   // 64 KB
    __shared__ unsigned char cnts[4096];     // clamped counts, one per block
    const int b = blockIdx.x;
    const int tid = threadIdx.x;
    uint4* img4 = reinterpret_cast<uint4*>(img);
#pragma unroll
    for (int j = 0; j < BAND_PIX / 4 / 1024; ++j)
        img4[j * 1024 + tid] = make_uint4(0u, 0u, 0u, 0u);
    // prefetch this band's counts, clamped to CAP (coalesced, exact staleness mask)
    for (int B = tid; B < NB; B += 1024) {
        unsigned int c = counts[(size_t)b * NB + B];
        cnts[B] = (unsigned char)min(c, (unsigned int)H_CAP);
    }
    __syncthreads();

    // stream all runs of this band: 320 B contiguous per run @ 80 KB stride,
    // full sectors, no dependent gates (mask from LDS)
    const int npairs = NB * (H_CAP / 2);  // pairs never straddle runs (CAP even)
    for (int pe = tid; pe < npairs; pe += 1024) {
        const unsigned int B = ((unsigned int)pe * 52429u) >> 20;  // pe / 20
        const unsigned int pslot = (unsigned int)pe - B * 20u;
        const unsigned int slot0 = pslot * 2u;
        const unsigned int cnt = cnts[B];
        const ulonglong2 v = *reinterpret_cast<const ulonglong2*>(
            bins + ((size_t)B * NBANDS + b) * H_CAP + slot0);
        if (slot0 < cnt)
            atomicMax(&img[(unsigned int)(v.x >> 32)], (unsigned int)v.x);
        if (slot0 + 1 < cnt)
            atomicMax(&img[(unsigned int)(v.y >> 32)], (unsigned int)v.y);
    }
    // per-band overflow list (~170 entries)
    unsigned int oc = bof_cur[b];
    if (oc > BOF_SLOTS) oc = BOF_SLOTS;
    const unsigned long long* bl = bof + (size_t)b * BOF_SLOTS;
    for (unsigned int s = tid; s < oc; s += 1024) {
        const unsigned long long v = bl[s];
        atomicMax(&img[(unsigned int)(v >> 32)], (unsigned int)v);
    }
    // global spill (expected empty)
    unsigned int sc = *spill_cur;
    if (sc > SP_CAP) sc = SP_CAP;
    for (unsigned int s = tid; s < sc; s += 1024) {
        const unsigned long long v = spill[s];
        const unsigned int pix = (unsigned int)(v >> 32);
        if ((pix >> 14) == (unsigned int)b)
            atomicMax(&img[pix & (BAND_PIX - 1)], (unsigned int)v);
    }
    __syncthreads();

    float4* out4 = reinterpret_cast<float4*>(out + (size_t)b * BAND_PIX);
#pragma unroll
    for (int j = 0; j < BAND_PIX / 4 / 1024; ++j) {
        const int idx = j * 1024 + tid;
        const uint4 k = img4[idx];
        float4 o;
        o.x = k.x ? ((float)(k.x & 0xFFu) + 0.5f) * (1.0f / 256.0f) : 0.0f;
        o.y = k.y ? ((float)(k.y & 0xFFu) + 0.5f) * (1.0f / 256.0f) : 0.0f;
        o.z = k.z ? ((float)(k.z & 0xFFu) + 0.5f) * (1.0f / 256.0f) : 0.0f;
        o.w = k.w ? ((float)(k.w & 0xFFu) + 0.5f) * (1.0f / 256.0f) : 0.0f;
        out4[idx] = o;
    }
}

// ---------------- Scheme A fallback: u64 atomicMax full image ----------------
__global__ __launch_bounds__(256) void scatter_pack_kernel(
    const float* __restrict__ x, unsigned long long* __restrict__ ws, int n) {
    int t = blockIdx.x * blockDim.x + threadIdx.x;
    int base = t * 4;
    if (base >= n) return;
    const float4* p = reinterpret_cast<const float4*>(x + (size_t)base * 3);
    float4 a = p[0], b = p[1], c = p[2];
    float xs[12] = {a.x, a.y, a.z, a.w, b.x, b.y, b.z, b.w, c.x, c.y, c.z, c.w};
#pragma unroll
    for (int k = 0; k < 4; ++k) {
        int i = base + k;
        if (i >= n) break;
        int i0 = min(max((int)floorf(xs[3*k+0] * (float)IMG_SIZE), 0), IMG_SIZE - 1);
        int i1 = min(max((int)floorf(xs[3*k+1] * (float)IMG_SIZE), 0), IMG_SIZE - 1);
        unsigned long long key =
            ((unsigned long long)(unsigned int)(i + 1) << 32) |
            (unsigned long long)__float_as_uint(xs[3*k+2]);
        atomicMax(&ws[i0 * IMG_SIZE + i1], key);
    }
}

__global__ __launch_bounds__(256) void finalize_kernel(
    const unsigned long long* __restrict__ ws, float* __restrict__ out) {
    int t = blockIdx.x * blockDim.x + threadIdx.x;
    const ulonglong2* w2 = reinterpret_cast<const ulonglong2*>(ws);
    ulonglong2 p0 = w2[(size_t)t * 2 + 0];
    ulonglong2 p1 = w2[(size_t)t * 2 + 1];
    float4 o;
    o.x = p0.x ? __uint_as_float((unsigned int)(p0.x & 0xFFFFFFFFull)) : 0.0f;
    o.y = p0.y ? __uint_as_float((unsigned int)(p0.y & 0xFFFFFFFFull)) : 0.0f;
    o.z = p1.x ? __uint_as_float((unsigned int)(p1.x & 0xFFFFFFFFull)) : 0.0f;
    o.w = p1.y ? __uint_as_float((unsigned int)(p1.y & 0xFFFFFFFFull)) : 0.0f;
    reinterpret_cast<float4*>(out)[t] = o;
}

// ---------------- Scheme B fallback: zero-workspace two-pass ----------------
__global__ __launch_bounds__(256) void scatter_idx_kernel(
    const float* __restrict__ x, unsigned int* __restrict__ img, int n) {
    int i = blockIdx.x * blockDim.x + threadIdx.x;
    if (i >= n) return;
    int i0 = min(max((int)floorf(x[3*i] * (float)IMG_SIZE), 0), IMG_SIZE - 1);
    int i1 = min(max((int)floorf(x[3*i+1] * (float)IMG_SIZE), 0), IMG_SIZE - 1);
    atomicMax(&img[i0 * IMG_SIZE + i1], (unsigned int)(i + 1));
}

__global__ __launch_bounds__(256) void resolve_idx_kernel(
    const float* __restrict__ x, unsigned int* __restrict__ img, int n) {
    int i = blockIdx.x * blockDim.x + threadIdx.x;
    if (i >= n) return;
    int i0 = min(max((int)floorf(x[3*i] * (float)IMG_SIZE), 0), IMG_SIZE - 1);
    int i1 = min(max((int)floorf(x[3*i+1] * (float)IMG_SIZE), 0), IMG_SIZE - 1);
    int flat = i0 * IMG_SIZE + i1;
    if (img[flat] == (unsigned int)(i + 1)) img[flat] = __float_as_uint(x[3*i+2]);
}

extern "C" void kernel_launch(void* const* d_in, const int* in_sizes, int n_in,
                              void* d_out, int out_size, void* d_ws, size_t ws_size,
                              hipStream_t stream) {
    const float* x = (const float*)d_in[0];
    const int n = in_sizes[0] / 3;
    float* out = (float*)d_out;

    const int NB = (n + H_CHUNK - 1) / H_CHUNK;  // 1024 for N=8.39M
    // ws layout: [bof_cur 1KB | spill_cur | pad 4KB][bof][spill][counts][bins]
    const size_t BOF_OFF = 4096;
    const size_t SPILL_OFF = BOF_OFF + (size_t)NBANDS * BOF_SLOTS * 8;
    const size_t COUNTS_OFF = SPILL_OFF + (size_t)SP_CAP * 8;
    size_t BINS_OFF = COUNTS_OFF + (size_t)NBANDS * NB * 4;
    BINS_OFF = (BINS_OFF + 255) & ~(size_t)255;
    const size_t J_NEED = BINS_OFF + (size_t)NB * NBANDS * H_CAP * 8;  // ~89.2 MB
    const size_t A_NEED = (size_t)NPIX * 8;  // 33.5 MB

    if (ws_size >= J_NEED && (long long)n + 1 < (1ll << 24)) {
        unsigned int* bof_cur = (unsigned int*)d_ws;
        unsigned int* spill_cur = (unsigned int*)((char*)d_ws + 1024);
        unsigned long long* bof = (unsigned long long*)((char*)d_ws + BOF_OFF);
        unsigned long long* spill = (unsigned long long*)((char*)d_ws + SPILL_OFF);
        unsigned int* counts = (unsigned int*)((char*)d_ws + COUNTS_OFF);
        unsigned long long* bins = (unsigned long long*)((char*)d_ws + BINS_OFF);
        hipMemsetAsync(d_ws, 0, 4096, stream);  // cursors only
        scatter_j_kernel<<<NB, H_TPB, 0, stream>>>(
            x, bins, counts, bof, bof_cur, spill, spill_cur, n, NB);
        resolve_j_kernel<<<NBANDS, 1024, 0, stream>>>(
            bins, counts, bof, bof_cur, spill, spill_cur, out, NB);
    } else if (ws_size >= A_NEED) {
        hipMemsetAsync(d_ws, 0, A_NEED, stream);
        const int nthreads = (n + 3) / 4;
        scatter_pack_kernel<<<(nthreads + 255) / 256, 256, 0, stream>>>(
            x, (unsigned long long*)d_ws, n);
        finalize_kernel<<<(NPIX / 4 + 255) / 256, 256, 0, stream>>>(
            (const unsigned long long*)d_ws, out);
    } else {
        hipMemsetAsync(d_out, 0, (size_t)NPIX * 4, stream);
        scatter_idx_kernel<<<(n + 255) / 256, 256, 0, stream>>>(
            x, (unsigned int*)d_out, n);
        resolve_idx_kernel<<<(n + 255) / 256, 256, 0, stream>>>(
            x, (unsigned int*)d_out, n);
    }
}

// Round 9
// 118.569 us; speedup vs baseline: 1.0015x; 1.0015x over previous
//
#include <hip/hip_runtime.h>

#define IMG_SIZE 2048
#define NPIX (IMG_SIZE * IMG_SIZE)
#define NBANDS 256
#define BAND_PIX (NPIX / NBANDS)   // 16384 pixels = 64 KB LDS u32

// ---- Scheme K: R6 scatter (per-block LDS-cursor overflow) + streaming resolve ----
// Bin entry u64 = (pos14 << 32) | key32 ; key32 = (i+1)<<8 | q8(value).
// max(key32) per pixel == max point index i == numpy last-write-wins.
// q8 dequant err <= ~1/512 << 2e-2 threshold. key32 == 0 <=> untouched pixel.
#define H_TPB 256
#define H_PPT 32
#define H_CHUNK (H_TPB * H_PPT)    // 8192 points/block -> mean 32/band
#define H_CAP 40                   // pairs/run = 20 (even -> ulonglong2 never straddles)
#define H_NB 4
#define H_BP 8
#define H_OFCAP 512                // per-block overflow segment (mean ~51 used)
#define SP_CAP 4096                // global spill (expected 0 entries)
#define MAX_NB 1024                // resolve LDS tables sized for <= 1024 blocks

__global__ __launch_bounds__(H_TPB) void scatter_k_kernel(
    const float* __restrict__ x, unsigned long long* __restrict__ bins,
    unsigned int* __restrict__ counts, unsigned long long* __restrict__ of,
    unsigned int* __restrict__ of_cnt, unsigned long long* __restrict__ spill,
    unsigned int* __restrict__ spill_cur, int n) {
    __shared__ unsigned int hist[NBANDS];
    __shared__ unsigned int ofc;
    const int tid = threadIdx.x;          // H_TPB == NBANDS == 256
    const int B = blockIdx.x;
    hist[tid] = 0;
    if (tid == 0) ofc = 0;
    __syncthreads();

    const int block_base = B * H_CHUNK;
    const size_t run_base = (size_t)B * NBANDS * H_CAP;  // block-major: 80 KB/block
    unsigned long long* ofseg = of + (size_t)B * H_OFCAP;

    if (block_base + H_CHUNK <= n) {
        // ---------- fast path: full chunk ----------
#pragma unroll
        for (int g = 0; g < H_NB; ++g) {
            const int p0 = block_base + g * (H_TPB * H_BP) + tid * H_BP;
            const float4* p = reinterpret_cast<const float4*>(x + (size_t)p0 * 3);
            float xs[24];
#pragma unroll
            for (int q = 0; q < 6; ++q) {
                const float4 v = p[q];
                xs[4*q+0] = v.x; xs[4*q+1] = v.y; xs[4*q+2] = v.z; xs[4*q+3] = v.w;
            }
            unsigned int bnd[H_BP], pos[H_BP], key[H_BP], r[H_BP];
#pragma unroll
            for (int j = 0; j < H_BP; ++j) {
                int i0 = (int)floorf(xs[3*j+0] * (float)IMG_SIZE);
                int i1 = (int)floorf(xs[3*j+1] * (float)IMG_SIZE);
                i0 = min(max(i0, 0), IMG_SIZE - 1);
                i1 = min(max(i1, 0), IMG_SIZE - 1);
                int q8 = (int)(xs[3*j+2] * 256.0f);
                q8 = min(max(q8, 0), 255);
                bnd[j] = (unsigned int)(i0 >> 3);
                pos[j] = (((unsigned int)i0 & 7u) << 11) | (unsigned int)i1;
                key[j] = (((unsigned int)(p0 + j) + 1u) << 8) | (unsigned int)q8;
            }
            // 8 independent LDS atomics -> pipelined
#pragma unroll
            for (int j = 0; j < H_BP; ++j) r[j] = atomicAdd(&hist[bnd[j]], 1u);
#pragma unroll
            for (int j = 0; j < H_BP; ++j) {
                const unsigned long long v =
                    ((unsigned long long)pos[j] << 32) | (unsigned long long)key[j];
                if (r[j] < H_CAP) {
                    bins[run_base + (size_t)bnd[j] * H_CAP + r[j]] = v;
                } else {
                    // per-block overflow segment: LDS cursor, zero global contention
                    const unsigned int s = atomicAdd(&ofc, 1u);
                    const unsigned long long ov =
                        ((unsigned long long)((bnd[j] << 14) | pos[j]) << 32) |
                        (unsigned long long)key[j];
                    if (s < H_OFCAP) {
                        ofseg[s] = ov;
                    } else {  // expected 0 ops ever
                        const unsigned int gs = atomicAdd(spill_cur, 1u);
                        if (gs < SP_CAP) spill[gs] = ov;
                    }
                }
            }
        }
    } else {
        // ---------- guarded tail path ----------
        const int hi = min(n, block_base + H_CHUNK);
        for (int i = block_base + tid; i < hi; i += H_TPB) {
            const float fx = x[3*i], fy = x[3*i+1], fv = x[3*i+2];
            int i0 = min(max((int)floorf(fx * (float)IMG_SIZE), 0), IMG_SIZE - 1);
            int i1 = min(max((int)floorf(fy * (float)IMG_SIZE), 0), IMG_SIZE - 1);
            int q8 = min(max((int)(fv * 256.0f), 0), 255);
            const unsigned int band = (unsigned int)(i0 >> 3);
            const unsigned int pos = (((unsigned int)i0 & 7u) << 11) | (unsigned int)i1;
            const unsigned int key = (((unsigned int)i + 1u) << 8) | (unsigned int)q8;
            const unsigned int r = atomicAdd(&hist[band], 1u);
            const unsigned long long v =
                ((unsigned long long)pos << 32) | (unsigned long long)key;
            if (r < H_CAP) {
                bins[run_base + (size_t)band * H_CAP + r] = v;
            } else {
                const unsigned int s = atomicAdd(&ofc, 1u);
                const unsigned long long ov =
                    ((unsigned long long)((band << 14) | pos) << 32) |
                    (unsigned long long)key;
                if (s < H_OFCAP) {
                    ofseg[s] = ov;
                } else {
                    const unsigned int gs = atomicAdd(spill_cur, 1u);
                    if (gs < SP_CAP) spill[gs] = ov;
                }
            }
        }
    }
    __syncthreads();
    counts[B * NBANDS + tid] = hist[tid];  // coalesced (R6-proven)
    if (tid == 0) of_cnt[B] = min(ofc, (unsigned int)H_OFCAP);
}

__global__ __launch_bounds__(1024) void resolve_k_kernel(
    const unsigned long long* __restrict__ bins,
    const unsigned int* __restrict__ counts,
    const unsigned long long* __restrict__ of,
    const unsigned int* __restrict__ of_cnt,
    const unsigned long long* __restrict__ spill,
    const unsigned int* __restrict__ spill_cur,
    float* __restrict__ out, int NB) {
    __shared__ unsigned int img[BAND_PIX];     // 64 KB
    __shared__ unsigned char cnts[MAX_NB];     // clamped bin counts per block
    __shared__ unsigned short ofcs[MAX_NB];    // overflow counts per block
    const int b = blockIdx.x;
    const int tid = threadIdx.x;
    uint4* img4 = reinterpret_cast<uint4*>(img);
#pragma unroll
    for (int j = 0; j < BAND_PIX / 4 / 1024; ++j)
        img4[j * 1024 + tid] = make_uint4(0u, 0u, 0u, 0u);
    // prefetch this band's counts (strided reads, L2/L3-hot) + overflow counts
    for (int B = tid; B < NB; B += 1024) {
        cnts[B] = (unsigned char)min(counts[(size_t)B * NBANDS + b],
                                     (unsigned int)H_CAP);
        ofcs[B] = (unsigned short)of_cnt[B];
    }
    __syncthreads();

    // stream all runs of this band: 320 B contiguous per run @ 80 KB stride,
    // no dependent gates (mask from LDS)
    const int npairs = NB * (H_CAP / 2);  // pairs never straddle runs (CAP even)
    for (int pe = tid; pe < npairs; pe += 1024) {
        const unsigned int B = ((unsigned int)pe * 52429u) >> 20;  // pe / 20
        const unsigned int slot0 = ((unsigned int)pe - B * 20u) * 2u;
        const unsigned int cnt = cnts[B];
        const ulonglong2 v = *reinterpret_cast<const ulonglong2*>(
            bins + ((size_t)B * NBANDS + b) * H_CAP + slot0);
        if (slot0 < cnt)
            atomicMax(&img[(unsigned int)(v.x >> 32)], (unsigned int)v.x);
        if (slot0 + 1 < cnt)
            atomicMax(&img[(unsigned int)(v.y >> 32)], (unsigned int)v.y);
    }
    // per-block overflow segments, filtered by band (L3-resident, ~420 KB real)
    const int warp = tid >> 6, lane = tid & 63;  // 16 waves
    for (int B = warp; B < NB; B += 16) {
        const unsigned int oc = ofcs[B];
        const unsigned long long* seg = of + (size_t)B * H_OFCAP;
        for (unsigned int s = lane; s < oc; s += 64) {
            const unsigned long long v = seg[s];
            const unsigned int pix = (unsigned int)(v >> 32);
            if ((pix >> 14) == (unsigned int)b)
                atomicMax(&img[pix & (BAND_PIX - 1)], (unsigned int)v);
        }
    }
    // global spill (expected empty)
    unsigned int sc = *spill_cur;
    if (sc > SP_CAP) sc = SP_CAP;
    for (unsigned int s = tid; s < sc; s += 1024) {
        const unsigned long long v = spill[s];
        const unsigned int pix = (unsigned int)(v >> 32);
        if ((pix >> 14) == (unsigned int)b)
            atomicMax(&img[pix & (BAND_PIX - 1)], (unsigned int)v);
    }
    __syncthreads();

    float4* out4 = reinterpret_cast<float4*>(out + (size_t)b * BAND_PIX);
#pragma unroll
    for (int j = 0; j < BAND_PIX / 4 / 1024; ++j) {
        const int idx = j * 1024 + tid;
        const uint4 k = img4[idx];
        float4 o;
        o.x = k.x ? ((float)(k.x & 0xFFu) + 0.5f) * (1.0f / 256.0f) : 0.0f;
        o.y = k.y ? ((float)(k.y & 0xFFu) + 0.5f) * (1.0f / 256.0f) : 0.0f;
        o.z = k.z ? ((float)(k.z & 0xFFu) + 0.5f) * (1.0f / 256.0f) : 0.0f;
        o.w = k.w ? ((float)(k.w & 0xFFu) + 0.5f) * (1.0f / 256.0f) : 0.0f;
        out4[idx] = o;
    }
}

// ---------------- Scheme A fallback: u64 atomicMax full image ----------------
__global__ __launch_bounds__(256) void scatter_pack_kernel(
    const float* __restrict__ x, unsigned long long* __restrict__ ws, int n) {
    int t = blockIdx.x * blockDim.x + threadIdx.x;
    int base = t * 4;
    if (base >= n) return;
    const float4* p = reinterpret_cast<const float4*>(x + (size_t)base * 3);
    float4 a = p[0], b = p[1], c = p[2];
    float xs[12] = {a.x, a.y, a.z, a.w, b.x, b.y, b.z, b.w, c.x, c.y, c.z, c.w};
#pragma unroll
    for (int k = 0; k < 4; ++k) {
        int i = base + k;
        if (i >= n) break;
        int i0 = min(max((int)floorf(xs[3*k+0] * (float)IMG_SIZE), 0), IMG_SIZE - 1);
        int i1 = min(max((int)floorf(xs[3*k+1] * (float)IMG_SIZE), 0), IMG_SIZE - 1);
        unsigned long long key =
            ((unsigned long long)(unsigned int)(i + 1) << 32) |
            (unsigned long long)__float_as_uint(xs[3*k+2]);
        atomicMax(&ws[i0 * IMG_SIZE + i1], key);
    }
}

__global__ __launch_bounds__(256) void finalize_kernel(
    const unsigned long long* __restrict__ ws, float* __restrict__ out) {
    int t = blockIdx.x * blockDim.x + threadIdx.x;
    const ulonglong2* w2 = reinterpret_cast<const ulonglong2*>(ws);
    ulonglong2 p0 = w2[(size_t)t * 2 + 0];
    ulonglong2 p1 = w2[(size_t)t * 2 + 1];
    float4 o;
    o.x = p0.x ? __uint_as_float((unsigned int)(p0.x & 0xFFFFFFFFull)) : 0.0f;
    o.y = p0.y ? __uint_as_float((unsigned int)(p0.y & 0xFFFFFFFFull)) : 0.0f;
    o.z = p1.x ? __uint_as_float((unsigned int)(p1.x & 0xFFFFFFFFull)) : 0.0f;
    o.w = p1.y ? __uint_as_float((unsigned int)(p1.y & 0xFFFFFFFFull)) : 0.0f;
    reinterpret_cast<float4*>(out)[t] = o;
}

// ---------------- Scheme B fallback: zero-workspace two-pass ----------------
__global__ __launch_bounds__(256) void scatter_idx_kernel(
    const float* __restrict__ x, unsigned int* __restrict__ img, int n) {
    int i = blockIdx.x * blockDim.x + threadIdx.x;
    if (i >= n) return;
    int i0 = min(max((int)floorf(x[3*i] * (float)IMG_SIZE), 0), IMG_SIZE - 1);
    int i1 = min(max((int)floorf(x[3*i+1] * (float)IMG_SIZE), 0), IMG_SIZE - 1);
    atomicMax(&img[i0 * IMG_SIZE + i1], (unsigned int)(i + 1));
}

__global__ __launch_bounds__(256) void resolve_idx_kernel(
    const float* __restrict__ x, unsigned int* __restrict__ img, int n) {
    int i = blockIdx.x * blockDim.x + threadIdx.x;
    if (i >= n) return;
    int i0 = min(max((int)floorf(x[3*i] * (float)IMG_SIZE), 0), IMG_SIZE - 1);
    int i1 = min(max((int)floorf(x[3*i+1] * (float)IMG_SIZE), 0), IMG_SIZE - 1);
    int flat = i0 * IMG_SIZE + i1;
    if (img[flat] == (unsigned int)(i + 1)) img[flat] = __float_as_uint(x[3*i+2]);
}

extern "C" void kernel_launch(void* const* d_in, const int* in_sizes, int n_in,
                              void* d_out, int out_size, void* d_ws, size_t ws_size,
                              hipStream_t stream) {
    const float* x = (const float*)d_in[0];
    const int n = in_sizes[0] / 3;
    float* out = (float*)d_out;

    const int NB = (n + H_CHUNK - 1) / H_CHUNK;  // 1024 for N=8.39M
    // ws layout: [spill_cur 256B][of_cnt][counts][of][spill][bins]
    const size_t OFCNT_OFF = 256;
    const size_t COUNTS_OFF = OFCNT_OFF + (size_t)NB * 4;
    size_t OF_OFF = COUNTS_OFF + (size_t)NB * NBANDS * 4;
    OF_OFF = (OF_OFF + 255) & ~(size_t)255;
    const size_t SPILL_OFF = OF_OFF + (size_t)NB * H_OFCAP * 8;
    const size_t BINS_OFF = SPILL_OFF + (size_t)SP_CAP * 8;
    const size_t K_NEED = BINS_OFF + (size_t)NB * NBANDS * H_CAP * 8;  // ~89 MB
    const size_t A_NEED = (size_t)NPIX * 8;  // 33.5 MB

    if (ws_size >= K_NEED && NB <= MAX_NB && (long long)n + 1 < (1ll << 24)) {
        unsigned int* spill_cur = (unsigned int*)d_ws;
        unsigned int* of_cnt = (unsigned int*)((char*)d_ws + OFCNT_OFF);
        unsigned int* counts = (unsigned int*)((char*)d_ws + COUNTS_OFF);
        unsigned long long* of = (unsigned long long*)((char*)d_ws + OF_OFF);
        unsigned long long* spill = (unsigned long long*)((char*)d_ws + SPILL_OFF);
        unsigned long long* bins = (unsigned long long*)((char*)d_ws + BINS_OFF);
        hipMemsetAsync(d_ws, 0, 256, stream);  // spill cursor only
        scatter_k_kernel<<<NB, H_TPB, 0, stream>>>(
            x, bins, counts, of, of_cnt, spill, spill_cur, n);
        resolve_k_kernel<<<NBANDS, 1024, 0, stream>>>(
            bins, counts, of, of_cnt, spill, spill_cur, out, NB);
    } else if (ws_size >= A_NEED) {
        hipMemsetAsync(d_ws, 0, A_NEED, stream);
        const int nthreads = (n + 3) / 4;
        scatter_pack_kernel<<<(nthreads + 255) / 256, 256, 0, stream>>>(
            x, (unsigned long long*)d_ws, n);
        finalize_kernel<<<(NPIX / 4 + 255) / 256, 256, 0, stream>>>(
            (const unsigned long long*)d_ws, out);
    } else {
        hipMemsetAsync(d_out, 0, (size_t)NPIX * 4, stream);
        scatter_idx_kernel<<<(n + 255) / 256, 256, 0, stream>>>(
            x, (unsigned int*)d_out, n);
        resolve_idx_kernel<<<(n + 255) / 256, 256, 0, stream>>>(
            x, (unsigned int*)d_out, n);
    }
}

// Round 10
// 88.562 us; speedup vs baseline: 1.3408x; 1.3388x over previous
//
#include <hip/hip_runtime.h>

#define IMG_SIZE 2048
#define NPIX (IMG_SIZE * IMG_SIZE)
#define NBANDS 256
#define BAND_PIX (NPIX / NBANDS)   // 16384 pixels = 64 KB LDS u32

// ---- Scheme N: two-pass cursor-reserved band-major binning (R3 refined) ----
// Bin entry u64 = (pos14 << 32) | key32 ; key32 = (i+1)<<8 | q8(value).
// max(key32) per pixel == max point index i == numpy last-write-wins.
// q8 dequant err <= 1/512 << 2e-2 threshold.
#define N_TPB 512
#define N_PPT 16
#define N_CHUNK (N_TPB * N_PPT)    // 8192 points/block -> mean 32/band
#define CAPN 36864                 // per-band region slots: mean 32768 + 22 sigma
#define SP_CAP 4096                // global spill (expected 0 entries)

__global__ __launch_bounds__(N_TPB) void scatter_n_kernel(
    const float* __restrict__ x, unsigned long long* __restrict__ bins,
    unsigned int* __restrict__ gcur, unsigned long long* __restrict__ spill,
    unsigned int* __restrict__ spill_cur, int n) {
    __shared__ unsigned int hist[NBANDS];
    __shared__ unsigned int base_[NBANDS];
    __shared__ unsigned int cur[NBANDS];
    const int tid = threadIdx.x;
    const int B = blockIdx.x;
    if (tid < NBANDS) { hist[tid] = 0; cur[tid] = 0; }
    __syncthreads();

    const int block_base = B * N_CHUNK;
    const bool full = (block_base + N_CHUNK <= n);

    // ---------------- pass 1: band histogram (no stores, no live state) ------
    if (full) {
#pragma unroll
        for (int g = 0; g < 2; ++g) {
            const int p0 = block_base + g * (N_TPB * 8) + tid * 8;
            const float4* p = reinterpret_cast<const float4*>(x + (size_t)p0 * 3);
            float xs[24];
#pragma unroll
            for (int q = 0; q < 6; ++q) {
                const float4 v = p[q];
                xs[4*q+0] = v.x; xs[4*q+1] = v.y; xs[4*q+2] = v.z; xs[4*q+3] = v.w;
            }
            unsigned int bnd[8];
#pragma unroll
            for (int j = 0; j < 8; ++j) {
                int i0 = (int)floorf(xs[3*j] * (float)IMG_SIZE);
                i0 = min(max(i0, 0), IMG_SIZE - 1);
                bnd[j] = (unsigned int)(i0 >> 3);
            }
#pragma unroll
            for (int j = 0; j < 8; ++j) atomicAdd(&hist[bnd[j]], 1u);
        }
    } else {
        const int hi = min(n, block_base + N_CHUNK);
        for (int i = block_base + tid; i < hi; i += N_TPB) {
            int i0 = min(max((int)floorf(x[3*i] * (float)IMG_SIZE), 0), IMG_SIZE - 1);
            atomicAdd(&hist[i0 >> 3], 1u);
        }
    }
    __syncthreads();

    // ------------- reserve: one distributed device atomic per (block,band) ---
    if (tid < NBANDS) {
        const unsigned int h = hist[tid];
        base_[tid] = h ? atomicAdd(&gcur[tid], h) : 0u;
    }
    __syncthreads();

    // ---------------- pass 2: re-read (L2-hot), rank, write ------------------
    if (full) {
#pragma unroll
        for (int g = 0; g < 2; ++g) {
            const int p0 = block_base + g * (N_TPB * 8) + tid * 8;
            const float4* p = reinterpret_cast<const float4*>(x + (size_t)p0 * 3);
            float xs[24];
#pragma unroll
            for (int q = 0; q < 6; ++q) {
                const float4 v = p[q];
                xs[4*q+0] = v.x; xs[4*q+1] = v.y; xs[4*q+2] = v.z; xs[4*q+3] = v.w;
            }
            unsigned int bnd[8], pos[8], key[8], r[8];
#pragma unroll
            for (int j = 0; j < 8; ++j) {
                int i0 = (int)floorf(xs[3*j+0] * (float)IMG_SIZE);
                int i1 = (int)floorf(xs[3*j+1] * (float)IMG_SIZE);
                i0 = min(max(i0, 0), IMG_SIZE - 1);
                i1 = min(max(i1, 0), IMG_SIZE - 1);
                int q8 = (int)(xs[3*j+2] * 256.0f);
                q8 = min(max(q8, 0), 255);
                bnd[j] = (unsigned int)(i0 >> 3);
                pos[j] = (((unsigned int)i0 & 7u) << 11) | (unsigned int)i1;
                key[j] = (((unsigned int)(p0 + j) + 1u) << 8) | (unsigned int)q8;
            }
#pragma unroll
            for (int j = 0; j < 8; ++j) r[j] = atomicAdd(&cur[bnd[j]], 1u);
#pragma unroll
            for (int j = 0; j < 8; ++j) {
                const unsigned int slot = base_[bnd[j]] + r[j];
                const unsigned long long v =
                    ((unsigned long long)pos[j] << 32) | (unsigned long long)key[j];
                if (slot < CAPN) {
                    bins[(size_t)bnd[j] * CAPN + slot] = v;
                } else {  // 22-sigma pathology only
                    const unsigned int gs = atomicAdd(spill_cur, 1u);
                    if (gs < SP_CAP)
                        spill[gs] = ((unsigned long long)((bnd[j] << 14) | pos[j]) << 32) |
                                    (unsigned long long)key[j];
                }
            }
        }
    } else {
        const int hi = min(n, block_base + N_CHUNK);
        for (int i = block_base + tid; i < hi; i += N_TPB) {
            const float fx = x[3*i], fy = x[3*i+1], fv = x[3*i+2];
            int i0 = min(max((int)floorf(fx * (float)IMG_SIZE), 0), IMG_SIZE - 1);
            int i1 = min(max((int)floorf(fy * (float)IMG_SIZE), 0), IMG_SIZE - 1);
            int q8 = min(max((int)(fv * 256.0f), 0), 255);
            const unsigned int band = (unsigned int)(i0 >> 3);
            const unsigned int pos = (((unsigned int)i0 & 7u) << 11) | (unsigned int)i1;
            const unsigned int key = (((unsigned int)i + 1u) << 8) | (unsigned int)q8;
            const unsigned int r = atomicAdd(&cur[band], 1u);
            const unsigned int slot = base_[band] + r;
            if (slot < CAPN) {
                bins[(size_t)band * CAPN + slot] =
                    ((unsigned long long)pos << 32) | (unsigned long long)key;
            } else {
                const unsigned int gs = atomicAdd(spill_cur, 1u);
                if (gs < SP_CAP)
                    spill[gs] = ((unsigned long long)((band << 14) | pos) << 32) |
                                (unsigned long long)key;
            }
        }
    }
}

__global__ __launch_bounds__(1024) void resolve_n_kernel(
    const unsigned long long* __restrict__ bins,
    const unsigned int* __restrict__ gcur,
    const unsigned long long* __restrict__ spill,
    const unsigned int* __restrict__ spill_cur,
    float* __restrict__ out) {
    __shared__ unsigned int img[BAND_PIX];  // 64 KB
    const int b = blockIdx.x;
    const int tid = threadIdx.x;
    uint4* img4 = reinterpret_cast<uint4*>(img);
#pragma unroll
    for (int j = 0; j < BAND_PIX / 4 / 1024; ++j)
        img4[j * 1024 + tid] = make_uint4(0u, 0u, 0u, 0u);
    __syncthreads();

    // stream this band's contiguous run [0, cnt)
    const unsigned int cnt = min(gcur[b], (unsigned int)CAPN);
    const ulonglong2* run2 =
        reinterpret_cast<const ulonglong2*>(bins + (size_t)b * CAPN);
    const unsigned int npairs = (cnt + 1u) >> 1;
    for (unsigned int pe = tid; pe < npairs; pe += 1024) {
        const ulonglong2 v = run2[pe];
        atomicMax(&img[(unsigned int)(v.x >> 32)], (unsigned int)v.x);
        if (2u * pe + 1u < cnt)
            atomicMax(&img[(unsigned int)(v.y >> 32)], (unsigned int)v.y);
    }
    // global spill (expected empty)
    unsigned int sc = *spill_cur;
    if (sc > SP_CAP) sc = SP_CAP;
    for (unsigned int s = tid; s < sc; s += 1024) {
        const unsigned long long v = spill[s];
        const unsigned int pix = (unsigned int)(v >> 32);
        if ((pix >> 14) == (unsigned int)b)
            atomicMax(&img[pix & (BAND_PIX - 1)], (unsigned int)v);
    }
    __syncthreads();

    float4* out4 = reinterpret_cast<float4*>(out + (size_t)b * BAND_PIX);
#pragma unroll
    for (int j = 0; j < BAND_PIX / 4 / 1024; ++j) {
        const int idx = j * 1024 + tid;
        const uint4 k = img4[idx];
        float4 o;
        o.x = k.x ? ((float)(k.x & 0xFFu) + 0.5f) * (1.0f / 256.0f) : 0.0f;
        o.y = k.y ? ((float)(k.y & 0xFFu) + 0.5f) * (1.0f / 256.0f) : 0.0f;
        o.z = k.z ? ((float)(k.z & 0xFFu) + 0.5f) * (1.0f / 256.0f) : 0.0f;
        o.w = k.w ? ((float)(k.w & 0xFFu) + 0.5f) * (1.0f / 256.0f) : 0.0f;
        out4[idx] = o;
    }
}

// ---------------- Scheme A fallback: u64 atomicMax full image ----------------
__global__ __launch_bounds__(256) void scatter_pack_kernel(
    const float* __restrict__ x, unsigned long long* __restrict__ ws, int n) {
    int t = blockIdx.x * blockDim.x + threadIdx.x;
    int base = t * 4;
    if (base >= n) return;
    const float4* p = reinterpret_cast<const float4*>(x + (size_t)base * 3);
    float4 a = p[0], b = p[1], c = p[2];
    float xs[12] = {a.x, a.y, a.z, a.w, b.x, b.y, b.z, b.w, c.x, c.y, c.z, c.w};
#pragma unroll
    for (int k = 0; k < 4; ++k) {
        int i = base + k;
        if (i >= n) break;
        int i0 = min(max((int)floorf(xs[3*k+0] * (float)IMG_SIZE), 0), IMG_SIZE - 1);
        int i1 = min(max((int)floorf(xs[3*k+1] * (float)IMG_SIZE), 0), IMG_SIZE - 1);
        unsigned long long key =
            ((unsigned long long)(unsigned int)(i + 1) << 32) |
            (unsigned long long)__float_as_uint(xs[3*k+2]);
        atomicMax(&ws[i0 * IMG_SIZE + i1], key);
    }
}

__global__ __launch_bounds__(256) void finalize_kernel(
    const unsigned long long* __restrict__ ws, float* __restrict__ out) {
    int t = blockIdx.x * blockDim.x + threadIdx.x;
    const ulonglong2* w2 = reinterpret_cast<const ulonglong2*>(ws);
    ulonglong2 p0 = w2[(size_t)t * 2 + 0];
    ulonglong2 p1 = w2[(size_t)t * 2 + 1];
    float4 o;
    o.x = p0.x ? __uint_as_float((unsigned int)(p0.x & 0xFFFFFFFFull)) : 0.0f;
    o.y = p0.y ? __uint_as_float((unsigned int)(p0.y & 0xFFFFFFFFull)) : 0.0f;
    o.z = p1.x ? __uint_as_float((unsigned int)(p1.x & 0xFFFFFFFFull)) : 0.0f;
    o.w = p1.y ? __uint_as_float((unsigned int)(p1.y & 0xFFFFFFFFull)) : 0.0f;
    reinterpret_cast<float4*>(out)[t] = o;
}

// ---------------- Scheme B fallback: zero-workspace two-pass ----------------
__global__ __launch_bounds__(256) void scatter_idx_kernel(
    const float* __restrict__ x, unsigned int* __restrict__ img, int n) {
    int i = blockIdx.x * blockDim.x + threadIdx.x;
    if (i >= n) return;
    int i0 = min(max((int)floorf(x[3*i] * (float)IMG_SIZE), 0), IMG_SIZE - 1);
    int i1 = min(max((int)floorf(x[3*i+1] * (float)IMG_SIZE), 0), IMG_SIZE - 1);
    atomicMax(&img[i0 * IMG_SIZE + i1], (unsigned int)(i + 1));
}

__global__ __launch_bounds__(256) void resolve_idx_kernel(
    const float* __restrict__ x, unsigned int* __restrict__ img, int n) {
    int i = blockIdx.x * blockDim.x + threadIdx.x;
    if (i >= n) return;
    int i0 = min(max((int)floorf(x[3*i] * (float)IMG_SIZE), 0), IMG_SIZE - 1);
    int i1 = min(max((int)floorf(x[3*i+1] * (float)IMG_SIZE), 0), IMG_SIZE - 1);
    int flat = i0 * IMG_SIZE + i1;
    if (img[flat] == (unsigned int)(i + 1)) img[flat] = __float_as_uint(x[3*i+2]);
}

extern "C" void kernel_launch(void* const* d_in, const int* in_sizes, int n_in,
                              void* d_out, int out_size, void* d_ws, size_t ws_size,
                              hipStream_t stream) {
    const float* x = (const float*)d_in[0];
    const int n = in_sizes[0] / 3;
    float* out = (float*)d_out;

    const int NB = (n + N_CHUNK - 1) / N_CHUNK;  // 1024 for N=8.39M
    // ws layout: [gcur 1KB | spill_cur | pad 4KB][spill 32KB][bins 75.5MB]
    const size_t SPILL_OFF = 4096;
    const size_t BINS_OFF = SPILL_OFF + (size_t)SP_CAP * 8;
    const size_t N_NEED = BINS_OFF + (size_t)NBANDS * CAPN * 8;  // ~75.5 MB
    const size_t A_NEED = (size_t)NPIX * 8;                       // 33.5 MB

    if (ws_size >= N_NEED && NB > 0 && (long long)n + 1 < (1ll << 24)) {
        unsigned int* gcur = (unsigned int*)d_ws;
        unsigned int* spill_cur = (unsigned int*)((char*)d_ws + 1024);
        unsigned long long* spill = (unsigned long long*)((char*)d_ws + SPILL_OFF);
        unsigned long long* bins = (unsigned long long*)((char*)d_ws + BINS_OFF);
        hipMemsetAsync(d_ws, 0, 4096, stream);  // gcur + spill_cur
        scatter_n_kernel<<<NB, N_TPB, 0, stream>>>(
            x, bins, gcur, spill, spill_cur, n);
        resolve_n_kernel<<<NBANDS, 1024, 0, stream>>>(
            bins, gcur, spill, spill_cur, out);
    } else if (ws_size >= A_NEED) {
        hipMemsetAsync(d_ws, 0, A_NEED, stream);
        const int nthreads = (n + 3) / 4;
        scatter_pack_kernel<<<(nthreads + 255) / 256, 256, 0, stream>>>(
            x, (unsigned long long*)d_ws, n);
        finalize_kernel<<<(NPIX / 4 + 255) / 256, 256, 0, stream>>>(
            (const unsigned long long*)d_ws, out);
    } else {
        hipMemsetAsync(d_out, 0, (size_t)NPIX * 4, stream);
        scatter_idx_kernel<<<(n + 255) / 256, 256, 0, stream>>>(
            x, (unsigned int*)d_out, n);
        resolve_idx_kernel<<<(n + 255) / 256, 256, 0, stream>>>(
            x, (unsigned int*)d_out, n);
    }
}